// Round 7
// baseline (256.474 us; speedup 1.0000x reference)
//
#include <hip/hip_runtime.h>
#include <math.h>

#define Vc 25
#define QSCALE 0.35355339059327373f   // DKH^-0.5

// may_alias: punned onto the unsigned short LDS array (TBAA safety).
typedef short bf16x8 __attribute__((ext_vector_type(8), may_alias));
typedef short bf16x4 __attribute__((ext_vector_type(4), may_alias));
typedef unsigned int u32a __attribute__((may_alias));
typedef float f32x4 __attribute__((ext_vector_type(4)));
typedef float f32x4a __attribute__((ext_vector_type(4), may_alias));

#define FENCE() asm volatile("" ::: "memory")

__device__ __forceinline__ unsigned short f2bf(float f) {
    unsigned u = __builtin_bit_cast(unsigned, f);
    u = (u + 0x7fff + ((u >> 16) & 1)) >> 16;   // RNE
    return (unsigned short)u;
}
__device__ __forceinline__ float bf2f(unsigned short h) {
    unsigned u = ((unsigned)h) << 16;
    return __builtin_bit_cast(float, u);
}

// 16-lane butterfly add via DPP (xor1, xor2, xor7, xor15 — wider steps valid
// because narrower steps make the groups uniform first). No DS-pipe traffic.
template<int CTRL>
__device__ __forceinline__ float dpp_add(float x) {
    int xi = __builtin_bit_cast(int, x);
    int yi = __builtin_amdgcn_update_dpp(0, xi, CTRL, 0xf, 0xf, true);
    return x + __builtin_bit_cast(float, yi);
}
__device__ __forceinline__ float row_sum16(float s) {
    s = dpp_add<0xB1>(s);    // quad_perm [1,0,3,2]  = xor 1
    s = dpp_add<0x4E>(s);    // quad_perm [2,3,0,1]  = xor 2
    s = dpp_add<0x141>(s);   // row_half_mirror      = xor 7 (groups-of-4 uniform)
    s = dpp_add<0x140>(s);   // row_mirror           = xor 15 (groups-of-8 uniform)
    return s;
}

// ---------------- LDS layout (u16 offsets), 21952 u16 = 43904 B -> 3 blocks/CU ----------------
// NOTE: B-frag b128 reads intentionally over-read past per-row valid data into
// neighboring initialized LDS (k>=8 quadrants are nulled by zero A-quadrants);
// the zero-init below is LOAD-BEARING — every reachable byte is zeroed-or-written.
#define QT_O   0       // [8 h]*520 + t*8 + d
#define KT_O   4160    // same layout for k
#define VS_O   8320    // [8 h]*584 + d*72 + t
#define OT_O   12992   // [64 t][40]
#define SCR_O  15552   // 4 x 1600 per-wave scratch: RELW [80 m][20] / ATTL [16 t][72] / XST alias
#define SMEM_U16 21952

__global__ __launch_bounds__(256, 3)
void tcn_attn(const float* __restrict__ x, const float* __restrict__ w_qkv,
              const float* __restrict__ b_qkv, const float* __restrict__ w_out,
              const float* __restrict__ b_out, const float* __restrict__ key_rel,
              float* __restrict__ y)
{
    __shared__ unsigned short sm[SMEM_U16];

    const int tid  = threadIdx.x;
    const int lane = tid & 63;
    const int w    = tid >> 6;
    const int li   = lane & 15;
    const int lq   = lane >> 4;
    const int koff = lq * 8;
    const int n    = blockIdx.x;
    const int b    = blockIdx.y;
    const int n1   = b / Vc;
    const int v    = b - n1 * Vc;
    const int t0   = n * 64;
    const int trow = 16 * w + li;
    const unsigned scr = SCR_O + w * 1600;

    const bf16x8 z8 = {0,0,0,0,0,0,0,0};
    const f32x4  z4 = {0.f,0.f,0.f,0.f};

    // ---- zero-init QT/KT/VS/OT incl. ALL pad slots ----
    for (int i = tid; i < 7776; i += 256)
        ((u32a*)sm)[i] = 0u;

    // ---- prefetch residual + init proj accumulators ----
    float xres[16];
    f32x4 pacc[4];
    #pragma unroll
    for (int mt = 0; mt < 4; ++mt)
        #pragma unroll
        for (int r = 0; r < 4; ++r) {
            int o = mt * 16 + lq * 4 + r;
            xres[mt * 4 + r] = x[((n1 * 64 + o) * 512 + t0 + 16 * w + li) * Vc + v];
            pacc[mt][r] = b_out[o];
        }

    // ---- stage x tile -> XST [t][72] bf16 (scratch region; disjoint from zeroed range) ----
    #pragma unroll
    for (int i = 0; i < 16; ++i) {
        int e = tid + 256 * i, t = e & 63, c = e >> 6;
        sm[SCR_O + t * 72 + c] = f2bf(x[((n1 * 64 + c) * 512 + t0 + t) * Vc + v]);
    }
    __syncthreads();

    // ---- qkv via MFMA; weight A-frags built in-registers from fp32 globals ----
    #pragma unroll
    for (int sec = 0; sec < 3; ++sec) {
        const int mt = sec * 4 + w;
        const int m  = mt * 16 + li;
        const float wscale = (sec == 0) ? QSCALE : 1.0f;
        bf16x8 a0, a1;
        {
            const float* p0 = w_qkv + m * 64 + koff;         // ks=0
            const float* p1 = w_qkv + m * 64 + 32 + koff;    // ks=1
            f32x4a v00 = *(const f32x4a*)p0, v01 = *(const f32x4a*)(p0 + 4);
            f32x4a v10 = *(const f32x4a*)p1, v11 = *(const f32x4a*)(p1 + 4);
            #pragma unroll
            for (int j = 0; j < 4; ++j) {
                a0[j]     = (short)f2bf(v00[j] * wscale);
                a0[4 + j] = (short)f2bf(v01[j] * wscale);
                a1[j]     = (short)f2bf(v10[j] * wscale);
                a1[4 + j] = (short)f2bf(v11[j] * wscale);
            }
        }
        f32x4 acc[4];
        #pragma unroll
        for (int nt = 0; nt < 4; ++nt) {
            #pragma unroll
            for (int r = 0; r < 4; ++r)
                acc[nt][r] = b_qkv[mt * 16 + lq * 4 + r] * wscale;
            bf16x8 b0 = *(const bf16x8*)(sm + SCR_O + (16 * nt + li) * 72 + koff);
            bf16x8 b1 = *(const bf16x8*)(sm + SCR_O + (16 * nt + li) * 72 + 32 + koff);
            acc[nt] = __builtin_amdgcn_mfma_f32_16x16x32_bf16(a0, b0, acc[nt], 0, 0, 0);
            acc[nt] = __builtin_amdgcn_mfma_f32_16x16x32_bf16(a1, b1, acc[nt], 0, 0, 0);
        }
        const int h2 = 2 * w + (lq >> 1);
        if (sec < 2) {
            const unsigned base = (sec == 0 ? QT_O : KT_O) + h2 * 520 + (lq & 1) * 4;
            #pragma unroll
            for (int nt = 0; nt < 4; ++nt) {
                bf16x4 p;
                p.x = (short)f2bf(acc[nt][0]);
                p.y = (short)f2bf(acc[nt][1]);
                p.z = (short)f2bf(acc[nt][2]);
                p.w = (short)f2bf(acc[nt][3]);
                *(bf16x4*)(sm + base + (16 * nt + li) * 8) = p;
            }
        } else {
            #pragma unroll
            for (int nt = 0; nt < 4; ++nt)
                #pragma unroll
                for (int r = 0; r < 4; ++r)
                    sm[VS_O + h2 * 584 + ((lq & 1) * 4 + r) * 72 + 16 * nt + li] = f2bf(acc[nt][r]);
        }
    }
    __syncthreads();
    // ======== no more barriers ========

    // key_rel B-frags from fp32 global (clamped OOB tail is finite garbage,
    // nulled by zero A-quadrants / never-gathered rows — same as round 6)
    bf16x8 br[5];
    #pragma unroll
    for (int j = 0; j < 5; ++j) {
        int base = (16 * (3 - w + j) + li) * 8 + koff;
        if (base + 7 <= 1015) {
            f32x4a v0 = *(const f32x4a*)(key_rel + base);
            f32x4a v1 = *(const f32x4a*)(key_rel + base + 4);
            #pragma unroll
            for (int jj = 0; jj < 4; ++jj) {
                br[j][jj]     = (short)f2bf(v0[jj]);
                br[j][4 + jj] = (short)f2bf(v1[jj]);
            }
        } else {
            #pragma unroll
            for (int jj = 0; jj < 8; ++jj) {
                int idx = base + jj; if (idx > 1015) idx = 1015;
                br[j][jj] = (short)f2bf(key_rel[idx]);
            }
        }
    }

    // front(h): aq/bk loads + QK^T and rel MFMAs into registers
    auto FRONT = [&](int h, f32x4* qk, f32x4* rl) {
        bf16x8 aq = *(const bf16x8*)(sm + QT_O + h * 520 + trow * 8 + koff);
        if (lane >= 16) aq = z8;                 // K=8 real; zero quadrants 1-3
        #pragma unroll
        for (int nt = 0; nt < 4; ++nt) {
            bf16x8 bk = *(const bf16x8*)(sm + KT_O + h * 520 + (16 * nt + li) * 8 + koff);
            qk[nt] = __builtin_amdgcn_mfma_f32_16x16x32_bf16(aq, bk, z4, 0, 0, 0);
        }
        #pragma unroll
        for (int j = 0; j < 5; ++j)
            rl[j] = __builtin_amdgcn_mfma_f32_16x16x32_bf16(aq, br[j], z4, 0, 0, 0);
    };

    f32x4 qk[4], rl[5];
    FRONT(0, qk, rl);

    #pragma unroll
    for (int h = 0; h < 8; ++h) {
        // rel window stores: [m'][tl], packed b64
        #pragma unroll
        for (int j = 0; j < 5; ++j) {
            bf16x4 p;
            p.x = (short)f2bf(rl[j][0]);
            p.y = (short)f2bf(rl[j][1]);
            p.z = (short)f2bf(rl[j][2]);
            p.w = (short)f2bf(rl[j][3]);
            *(bf16x4*)(sm + scr + (16 * j + li) * 20 + 4 * lq) = p;
        }
        // pipeline: next head's front work fills this head's softmax window
        f32x4 qkn[4], rln[5];
        if (h < 7) FRONT(h + 1, qkn, rln);
        // prefetch out-proj A-frags (consumed after AV, ~400 cyc of slack)
        bf16x8 ao[4];
        if ((h & 3) == 3) {
            const int g = h >> 2;
            #pragma unroll
            for (int mt = 0; mt < 4; ++mt) {
                const float* p0 = w_out + (mt * 16 + li) * 64 + g * 32 + koff;
                f32x4a v0 = *(const f32x4a*)p0, v1 = *(const f32x4a*)(p0 + 4);
                #pragma unroll
                for (int jj = 0; jj < 4; ++jj) {
                    ao[mt][jj]     = (short)f2bf(v0[jj]);
                    ao[mt][4 + jj] = (short)f2bf(v1[jj]);
                }
            }
        }
        FENCE();   // rel stores stay above the gather reads
        // gather (m' = s - tl + 15) + exp + row sums
        float ex[4][4], lsum[4] = {0.f, 0.f, 0.f, 0.f};
        #pragma unroll
        for (int nt = 0; nt < 4; ++nt)
            #pragma unroll
            for (int r = 0; r < 4; ++r) {
                int mp = 16 * nt + li - 4 * lq - r + 15;
                float rv = bf2f(sm[scr + mp * 20 + 4 * lq + r]);
                float e = __expf(qk[nt][r] + rv);
                ex[nt][r] = e;
                lsum[r] += e;
            }
        FENCE();   // gather reads stay above ATTL overwrites
        float linv[4];
        #pragma unroll
        for (int r = 0; r < 4; ++r)
            linv[r] = 1.0f / row_sum16(lsum[r]);
        // UNNORMALIZED att -> ATTL [tl][72] (1/sum folded into OT store)
        #pragma unroll
        for (int nt = 0; nt < 4; ++nt)
            #pragma unroll
            for (int r = 0; r < 4; ++r)
                sm[scr + (4 * lq + r) * 72 + 16 * nt + li] = f2bf(ex[nt][r]);
        FENCE();   // ATTL stores before AV frag reads
        // AV
        f32x4 av = z4;
        #pragma unroll
        for (int ks = 0; ks < 2; ++ks) {
            bf16x8 aa = *(const bf16x8*)(sm + scr + li * 72 + ks * 32 + koff);
            bf16x8 bv = *(const bf16x8*)(sm + VS_O + h * 584 + (li & 7) * 72 + ks * 32 + koff);
            av = __builtin_amdgcn_mfma_f32_16x16x32_bf16(aa, bv, av, 0, 0, 0);
        }
        if (li < 8) {
            #pragma unroll
            for (int r = 0; r < 4; ++r)
                sm[OT_O + (16 * w + 4 * lq + r) * 40 + (h & 3) * 8 + li] = f2bf(av[r] * linv[r]);
        }
        // out-proj every 4 heads: K=32 dense, accumulates in pacc
        if ((h & 3) == 3) {
            FENCE();   // OT stores before bo read
            bf16x8 bo = *(const bf16x8*)(sm + OT_O + trow * 40 + koff);
            #pragma unroll
            for (int mt = 0; mt < 4; ++mt)
                pacc[mt] = __builtin_amdgcn_mfma_f32_16x16x32_bf16(ao[mt], bo, pacc[mt], 0, 0, 0);
        }
        FENCE();   // next head's rel stores stay below this head's AV/OT reads
        if (h < 7) {
            #pragma unroll
            for (int i = 0; i < 4; ++i) qk[i] = qkn[i];
            #pragma unroll
            for (int j = 0; j < 5; ++j) rl[j] = rln[j];
        }
    }

    // ---- epilogue: residual (prefetched fp32) + relu ----
    #pragma unroll
    for (int mt = 0; mt < 4; ++mt)
        #pragma unroll
        for (int r = 0; r < 4; ++r) {
            int o = mt * 16 + lq * 4 + r;
            int idx = ((n1 * 64 + o) * 512 + t0 + 16 * w + li) * Vc + v;
            y[idx] = fmaxf(pacc[mt][r] + xres[mt * 4 + r], 0.f);
        }
}

extern "C" void kernel_launch(void* const* d_in, const int* in_sizes, int n_in,
                              void* d_out, int out_size, void* d_ws, size_t ws_size,
                              hipStream_t stream) {
    const float* x       = (const float*)d_in[0];
    const float* w_qkv   = (const float*)d_in[1];
    const float* b_qkv   = (const float*)d_in[2];
    const float* w_out   = (const float*)d_in[3];
    const float* b_out   = (const float*)d_in[4];
    const float* key_rel = (const float*)d_in[5];
    float* y = (float*)d_out;

    dim3 grid(512 / 64, 400);   // (8, 400)
    tcn_attn<<<grid, dim3(256), 0, stream>>>(x, w_qkv, b_qkv, w_out, b_out, key_rel, y);
}

// Round 8
// 229.214 us; speedup vs baseline: 1.1189x; 1.1189x over previous
//
#include <hip/hip_runtime.h>
#include <math.h>

#define Vc 25
#define QSCALE 0.35355339059327373f   // DKH^-0.5

// may_alias: punned onto the unsigned short LDS/ws arrays (TBAA safety).
typedef short bf16x8 __attribute__((ext_vector_type(8), may_alias));
typedef unsigned int u32x2a __attribute__((ext_vector_type(2), may_alias));
typedef float f32x4 __attribute__((ext_vector_type(4)));

#define FENCE() asm volatile("" ::: "memory")

// RNE (prep path only — off the critical kernel)
__device__ __forceinline__ unsigned short f2bf(float f) {
    unsigned u = __builtin_bit_cast(unsigned, f);
    u = (u + 0x7fff + ((u >> 16) & 1)) >> 16;
    return (unsigned short)u;
}
// fast round-to-nearest (ties away): 2 VALU
__device__ __forceinline__ unsigned short f2bf_fast(float f) {
    unsigned u = __builtin_bit_cast(unsigned, f) + 0x8000u;
    return (unsigned short)(u >> 16);
}
// pack two floats -> two bf16 in one u32: 2 add + 1 perm
__device__ __forceinline__ unsigned pkbf(float lo, float hi) {
    unsigned a = __builtin_bit_cast(unsigned, lo) + 0x8000u;
    unsigned b = __builtin_bit_cast(unsigned, hi) + 0x8000u;
    return __builtin_amdgcn_perm(b, a, 0x07060302);   // D = [b.hi16 : a.hi16]
}
__device__ __forceinline__ float bf2f(unsigned short h) {
    unsigned u = ((unsigned)h) << 16;
    return __builtin_bit_cast(float, u);
}

// 16-lane butterfly add via DPP (xor1, xor2, xor7, xor15 — wider steps valid
// because narrower steps make the groups uniform first). No DS-pipe traffic.
template<int CTRL>
__device__ __forceinline__ float dpp_add(float x) {
    int xi = __builtin_bit_cast(int, x);
    int yi = __builtin_amdgcn_update_dpp(0, xi, CTRL, 0xf, 0xf, true);
    return x + __builtin_bit_cast(float, yi);
}
__device__ __forceinline__ float row_sum16(float s) {
    s = dpp_add<0xB1>(s);    // quad_perm [1,0,3,2]  = xor 1
    s = dpp_add<0x4E>(s);    // quad_perm [2,3,0,1]  = xor 2
    s = dpp_add<0x141>(s);   // row_half_mirror      = xor 7
    s = dpp_add<0x140>(s);   // row_mirror           = xor 15
    return s;
}

// ---------------- ws layout (u16 element offsets) ----------------
#define WQA_O 0        // 12288: qkv weight A-frags [12 mt][2 ks][64 lane][8], q pre-scaled
#define BQ_O  12288    // 384 u16 = 192 f32 bias (q part pre-scaled)
#define KRT_O 12672    // 1088: key_rel [136 m][8 d], rows >=127 zeroed
#define WOA_O 13760    // 4096: out-proj A-frags [2 g][4 mt][64 lane][8], K=32 dense

// ---------------- prep: weight swizzle into d_ws (runs every call) ----------------
__global__ void prep_kernel(const float* __restrict__ w_qkv, const float* __restrict__ b_qkv,
                            const float* __restrict__ w_out, const float* __restrict__ key_rel,
                            unsigned short* __restrict__ ws)
{
    const int gid = blockIdx.x * 256 + threadIdx.x;
    const int gsz = gridDim.x * 256;
    for (int id = gid; id < 12288; id += gsz) {
        int j = id & 7, lane = (id >> 3) & 63, ks = (id >> 9) & 1, mt = id >> 10;
        int m = mt * 16 + (lane & 15);
        int k = ks * 32 + (lane >> 4) * 8 + j;
        ws[WQA_O + id] = f2bf(w_qkv[m * 64 + k] * (m < 64 ? QSCALE : 1.f));
    }
    float* bq = (float*)(ws + BQ_O);
    for (int id = gid; id < 192; id += gsz)
        bq[id] = b_qkv[id] * (id < 64 ? QSCALE : 1.f);
    for (int id = gid; id < 1088; id += gsz) {
        int d = id & 7, m = id >> 3;
        ws[KRT_O + id] = (m < 127) ? f2bf(key_rel[m * 8 + d]) : (unsigned short)0;
    }
    for (int id = gid; id < 4096; id += gsz) {
        int j = id & 7, lane = (id >> 3) & 63, mtg = id >> 9;   // mtg = g*4+mt
        int m = (mtg & 3) * 16 + (lane & 15);
        int k = (mtg >> 2) * 32 + (lane >> 4) * 8 + j;
        ws[WOA_O + id] = f2bf(w_out[m * 64 + k]);
    }
}

// ---------------- LDS layout (u16 offsets), 21952 u16 = 43904 B -> 3 blocks/CU ----------------
// Zero-init of [0, SCR_O) is LOAD-BEARING: B-frag b128 reads over-read into pad
// slots (nulled by zero A-quadrants) — every reachable byte must be zeroed-or-written.
#define QT_O   0       // [8 h]*520 + t*8 + d
#define KT_O   4160    // same layout for k
#define VS_O   8320    // [8 h]*584 + d*72 + t
#define OT_O   12992   // [64 t][40]
#define SCR_O  15552   // 4 x 1600 per-wave scratch: RELW [80 m][20] / ATTL [16 t][72] / XST alias
#define SMEM_U16 21952

__global__ __launch_bounds__(256, 3)
void tcn_attn(const float* __restrict__ x, const float* __restrict__ b_out,
              const unsigned short* __restrict__ ws, float* __restrict__ y)
{
    __shared__ unsigned short sm[SMEM_U16];

    const int tid  = threadIdx.x;
    const int lane = tid & 63;
    const int w    = tid >> 6;
    const int li   = lane & 15;
    const int lq   = lane >> 4;
    const int koff = lq * 8;
    const int n    = blockIdx.x;
    const int b    = blockIdx.y;
    const int n1   = b / Vc;
    const int v    = b - n1 * Vc;
    const int t0   = n * 64;
    const int trow = 16 * w + li;
    const unsigned scr = SCR_O + w * 1600;

    const bf16x8 z8 = {0,0,0,0,0,0,0,0};
    const f32x4  z4 = {0.f,0.f,0.f,0.f};

    // ---- zero-init [0, SCR_O) with b128 stores: 1944 slots of 8 u16 ----
    for (int i = tid; i < 1944; i += 256)
        *(bf16x8*)(sm + i * 8) = z8;

    // ---- prefetch residual + init proj accumulators ----
    float xres[16];
    f32x4 pacc[4];
    #pragma unroll
    for (int mt = 0; mt < 4; ++mt)
        #pragma unroll
        for (int r = 0; r < 4; ++r) {
            int o = mt * 16 + lq * 4 + r;
            xres[mt * 4 + r] = x[((n1 * 64 + o) * 512 + t0 + 16 * w + li) * Vc + v];
            pacc[mt][r] = b_out[o];
        }

    // ---- stage x tile -> XST [t][72] bf16 (scratch region; disjoint from zeroed range) ----
    #pragma unroll
    for (int i = 0; i < 16; ++i) {
        int e = tid + 256 * i, t = e & 63, c = e >> 6;
        sm[SCR_O + t * 72 + c] = f2bf_fast(x[((n1 * 64 + c) * 512 + t0 + t) * Vc + v]);
    }
    __syncthreads();

    // ---- qkv via MFMA; A-frags from prep-swizzled ws; packed b64 writes to QT/KT ----
    const unsigned short* wq = ws + WQA_O;
    const float* bq = (const float*)(ws + BQ_O);
    #pragma unroll
    for (int sec = 0; sec < 3; ++sec) {
        const int mt = sec * 4 + w;
        bf16x8 a0 = *(const bf16x8*)(wq + ((mt * 2 + 0) * 64 + lane) * 8);
        bf16x8 a1 = *(const bf16x8*)(wq + ((mt * 2 + 1) * 64 + lane) * 8);
        f32x4 acc[4];
        #pragma unroll
        for (int nt = 0; nt < 4; ++nt) {
            #pragma unroll
            for (int r = 0; r < 4; ++r) acc[nt][r] = bq[mt * 16 + lq * 4 + r];
            bf16x8 b0 = *(const bf16x8*)(sm + SCR_O + (16 * nt + li) * 72 + koff);
            bf16x8 b1 = *(const bf16x8*)(sm + SCR_O + (16 * nt + li) * 72 + 32 + koff);
            acc[nt] = __builtin_amdgcn_mfma_f32_16x16x32_bf16(a0, b0, acc[nt], 0, 0, 0);
            acc[nt] = __builtin_amdgcn_mfma_f32_16x16x32_bf16(a1, b1, acc[nt], 0, 0, 0);
        }
        const int h2 = 2 * w + (lq >> 1);
        if (sec < 2) {
            const unsigned base = (sec == 0 ? QT_O : KT_O) + h2 * 520 + (lq & 1) * 4;
            #pragma unroll
            for (int nt = 0; nt < 4; ++nt) {
                u32x2a p;
                p.x = pkbf(acc[nt][0], acc[nt][1]);
                p.y = pkbf(acc[nt][2], acc[nt][3]);
                *(u32x2a*)(sm + base + (16 * nt + li) * 8) = p;   // ds_write_b64
            }
        } else {
            #pragma unroll
            for (int nt = 0; nt < 4; ++nt)
                #pragma unroll
                for (int r = 0; r < 4; ++r)
                    sm[VS_O + h2 * 584 + ((lq & 1) * 4 + r) * 72 + 16 * nt + li] = f2bf_fast(acc[nt][r]);
        }
    }
    __syncthreads();
    // ======== no more barriers ========

    // key_rel B-frags (head-invariant, prep-zeroed rows >=127)
    bf16x8 br[5];
    #pragma unroll
    for (int j = 0; j < 5; ++j)
        br[j] = *(const bf16x8*)(ws + KRT_O + (16 * (3 - w + j) + li) * 8 + koff);

    // front(h): aq/bk loads + QK^T and rel MFMAs into registers
    auto FRONT = [&](int h, f32x4* qk, f32x4* rl) {
        bf16x8 aq = *(const bf16x8*)(sm + QT_O + h * 520 + trow * 8 + koff);
        if (lane >= 16) aq = z8;                 // K=8 real; zero quadrants 1-3
        #pragma unroll
        for (int nt = 0; nt < 4; ++nt) {
            bf16x8 bk = *(const bf16x8*)(sm + KT_O + h * 520 + (16 * nt + li) * 8 + koff);
            qk[nt] = __builtin_amdgcn_mfma_f32_16x16x32_bf16(aq, bk, z4, 0, 0, 0);
        }
        #pragma unroll
        for (int j = 0; j < 5; ++j)
            rl[j] = __builtin_amdgcn_mfma_f32_16x16x32_bf16(aq, br[j], z4, 0, 0, 0);
    };

    f32x4 qk[4], rl[5];
    FRONT(0, qk, rl);

    #pragma unroll
    for (int h = 0; h < 8; ++h) {
        // rel window stores: [m'][tl], packed b64
        #pragma unroll
        for (int j = 0; j < 5; ++j) {
            u32x2a p;
            p.x = pkbf(rl[j][0], rl[j][1]);
            p.y = pkbf(rl[j][2], rl[j][3]);
            *(u32x2a*)(sm + scr + (16 * j + li) * 20 + 4 * lq) = p;
        }
        // pipeline: next head's front work fills this head's softmax window
        f32x4 qkn[4], rln[5];
        if (h < 7) FRONT(h + 1, qkn, rln);
        // prefetch out-proj A-frags from ws (consumed after AV)
        bf16x8 ao[4];
        if ((h & 3) == 3) {
            const int g = h >> 2;
            #pragma unroll
            for (int mt = 0; mt < 4; ++mt)
                ao[mt] = *(const bf16x8*)(ws + WOA_O + ((g * 4 + mt) * 64 + lane) * 8);
        }
        FENCE();   // rel stores stay above the gather reads
        // gather (m' = s - tl + 15) + exp + row sums
        float ex[4][4], lsum[4] = {0.f, 0.f, 0.f, 0.f};
        #pragma unroll
        for (int nt = 0; nt < 4; ++nt)
            #pragma unroll
            for (int r = 0; r < 4; ++r) {
                int mp = 16 * nt + li - 4 * lq - r + 15;
                float rv = bf2f(sm[scr + mp * 20 + 4 * lq + r]);
                float e = __expf(qk[nt][r] + rv);
                ex[nt][r] = e;
                lsum[r] += e;
            }
        FENCE();   // gather reads stay above ATTL overwrites
        float linv[4];
        #pragma unroll
        for (int r = 0; r < 4; ++r)
            linv[r] = 1.0f / row_sum16(lsum[r]);
        // UNNORMALIZED att -> ATTL [tl][72] (1/sum folded into OT store)
        #pragma unroll
        for (int nt = 0; nt < 4; ++nt)
            #pragma unroll
            for (int r = 0; r < 4; ++r)
                sm[scr + (4 * lq + r) * 72 + 16 * nt + li] = f2bf_fast(ex[nt][r]);
        FENCE();   // ATTL stores before AV frag reads
        // AV
        f32x4 av = z4;
        #pragma unroll
        for (int ks = 0; ks < 2; ++ks) {
            bf16x8 aa = *(const bf16x8*)(sm + scr + li * 72 + ks * 32 + koff);
            bf16x8 bv = *(const bf16x8*)(sm + VS_O + h * 584 + (li & 7) * 72 + ks * 32 + koff);
            av = __builtin_amdgcn_mfma_f32_16x16x32_bf16(aa, bv, av, 0, 0, 0);
        }
        if (li < 8) {
            #pragma unroll
            for (int r = 0; r < 4; ++r)
                sm[OT_O + (16 * w + 4 * lq + r) * 40 + (h & 3) * 8 + li] = f2bf_fast(av[r] * linv[r]);
        }
        // out-proj every 4 heads: K=32 dense, accumulates in pacc
        if ((h & 3) == 3) {
            FENCE();   // OT stores before bo read
            bf16x8 bo = *(const bf16x8*)(sm + OT_O + trow * 40 + koff);
            #pragma unroll
            for (int mt = 0; mt < 4; ++mt)
                pacc[mt] = __builtin_amdgcn_mfma_f32_16x16x32_bf16(ao[mt], bo, pacc[mt], 0, 0, 0);
        }
        FENCE();   // next head's rel stores stay below this head's AV/OT reads
        if (h < 7) {
            #pragma unroll
            for (int i = 0; i < 4; ++i) qk[i] = qkn[i];
            #pragma unroll
            for (int j = 0; j < 5; ++j) rl[j] = rln[j];
        }
    }

    // ---- epilogue: residual (prefetched fp32) + relu ----
    #pragma unroll
    for (int mt = 0; mt < 4; ++mt)
        #pragma unroll
        for (int r = 0; r < 4; ++r) {
            int o = mt * 16 + lq * 4 + r;
            int idx = ((n1 * 64 + o) * 512 + t0 + 16 * w + li) * Vc + v;
            y[idx] = fmaxf(pacc[mt][r] + xres[mt * 4 + r], 0.f);
        }
}

extern "C" void kernel_launch(void* const* d_in, const int* in_sizes, int n_in,
                              void* d_out, int out_size, void* d_ws, size_t ws_size,
                              hipStream_t stream) {
    const float* x       = (const float*)d_in[0];
    const float* w_qkv   = (const float*)d_in[1];
    const float* b_qkv   = (const float*)d_in[2];
    const float* w_out   = (const float*)d_in[3];
    const float* b_out   = (const float*)d_in[4];
    const float* key_rel = (const float*)d_in[5];
    float* y = (float*)d_out;
    unsigned short* ws = (unsigned short*)d_ws;

    prep_kernel<<<dim3(96), dim3(256), 0, stream>>>(w_qkv, b_qkv, w_out, key_rel, ws);
    dim3 grid(512 / 64, 400);   // (8, 400)
    tcn_attn<<<grid, dim3(256), 0, stream>>>(x, b_out, ws, y);
}